// Round 6
// baseline (199.619 us; speedup 1.0000x reference)
//
#include <hip/hip_runtime.h>
#include <hip/hip_fp16.h>

// Problem constants (from reference)
#define BATCH 2
#define NS 128        // input spatial dim (X=Y=Z=128)
#define NB 64         // bricks per dim (2x2x2 voxel bricks)
#define ND 96         // output grid per spatial dim

constexpr int PPB   = ND * ND * ND;            // 884736 points per batch
constexpr int TOTAL = BATCH * PPB;             // 1769472
constexpr int BRICKS_PER_BATCH = NB * NB * NB; // 262144
constexpr int TOTAL_BRICKS = BATCH * BRICKS_PER_BATCH;
constexpr size_t WS_NEEDED = (size_t)TOTAL_BRICKS * 64; // 33.55 MB fp16 bricks

// native clang vector type: accepted by __builtin_nontemporal_*
typedef float  fx4 __attribute__((ext_vector_type(4)));

__device__ __forceinline__ float4 f4_lerp(float4 a, float4 b, float t) {
    float4 r;
    r.x = fmaf(b.x - a.x, t, a.x);
    r.y = fmaf(b.y - a.y, t, a.y);
    r.z = fmaf(b.z - a.z, t, a.z);
    r.w = fmaf(b.w - a.w, t, a.w);
    return r;
}

// ---------------- Repack: fp32 linear -> fp16 2x2x2 bricks (64B/brick) ----
__global__ __launch_bounds__(256) void repack_fp16_bricks(
    const fx4* __restrict__ in, uint2* __restrict__ bricks)
{
    int g = blockIdx.x * 256 + threadIdx.x;   // grid sized exactly
    int t = g >> 3;
    int l = g & 7;
    int lx = (l >> 2) & 1, ly = (l >> 1) & 1, lz = l & 1;
    int b  = t >> 18;              // / 262144
    int r  = t & 262143;
    int x  = ((r >> 12) << 1) + lx;
    int y  = (((r >> 6) & 63) << 1) + ly;
    int z  = ((r & 63) << 1) + lz;

    // input is read exactly once -> non-temporal
    fx4 v = __builtin_nontemporal_load(&in[(((size_t)b * NS + x) * NS + y) * NS + z]);
    __half2 h0 = __float22half2_rn(make_float2(v.x, v.y));
    __half2 h1 = __float22half2_rn(make_float2(v.z, v.w));
    uint2 p;
    p.x = *(const unsigned int*)&h0;
    p.y = *(const unsigned int*)&h1;
    bricks[g] = p;
}

__device__ __forceinline__ float4 vox_to_f4(uint2 v) {
    __half2 a = *(const __half2*)&v.x;
    __half2 b = *(const __half2*)&v.y;
    float2 f0 = __half22float2(a);
    float2 f1 = __half22float2(b);
    return make_float4(f0.x, f0.y, f1.x, f1.y);
}

// voxel (x,y,z) -> uint2 index into brick buffer (8B units)
__device__ __forceinline__ int brick_off(int x, int y, int z) {
    int bidx = (((x >> 1) * NB) + (y >> 1)) * NB + (z >> 1);
    return (bidx << 3) + ((x & 1) << 2) + ((y & 1) << 1) + (z & 1);
}

__device__ __forceinline__ void point_setup(
    float cx, float cy, float cz,
    int& o000, int& o001, int& o010, int& o011,
    int& o100, int& o101, int& o110, int& o111,
    float& wx, float& wy, float& wz)
{
    const float fx = floorf(cx), fy = floorf(cy), fz = floorf(cz);
    wx = cx - fx; wy = cy - fy; wz = cz - fz;
    int x0 = max(0, min((int)fx,     NS - 1));
    int x1 = max(0, min((int)fx + 1, NS - 1));
    int y0 = max(0, min((int)fy,     NS - 1));
    int y1 = max(0, min((int)fy + 1, NS - 1));
    int z0 = max(0, min((int)fz,     NS - 1));
    int z1 = max(0, min((int)fz + 1, NS - 1));
    o000 = brick_off(x0, y0, z0); o001 = brick_off(x0, y0, z1);
    o010 = brick_off(x0, y1, z0); o011 = brick_off(x0, y1, z1);
    o100 = brick_off(x1, y0, z0); o101 = brick_off(x1, y0, z1);
    o110 = brick_off(x1, y1, z0); o111 = brick_off(x1, y1, z1);
}

__device__ __forceinline__ void nt_store4(float4 v, fx4* p) {
    fx4 t; t.x = v.x; t.y = v.y; t.z = v.z; t.w = v.w;
    __builtin_nontemporal_store(t, p);
}

// ---------------- Resample: 2 points per thread (batch0 + batch1) ---------
__global__ __launch_bounds__(256) void resample_bricks2(
    const uint2* __restrict__ bricks,
    const float* __restrict__ coords,
    fx4*         __restrict__ out)
{
    int idx = blockIdx.x * 256 + threadIdx.x;   // 0 .. PPB-1 (grid exact)
    const int idxB = idx + PPB;

    // coords: streamed once -> non-temporal loads
    const float axc = __builtin_nontemporal_load(&coords[3 * idx + 0]);
    const float ayc = __builtin_nontemporal_load(&coords[3 * idx + 1]);
    const float azc = __builtin_nontemporal_load(&coords[3 * idx + 2]);
    const float bxc = __builtin_nontemporal_load(&coords[3 * idxB + 0]);
    const float byc = __builtin_nontemporal_load(&coords[3 * idxB + 1]);
    const float bzc = __builtin_nontemporal_load(&coords[3 * idxB + 2]);

    int a000,a001,a010,a011,a100,a101,a110,a111;
    int b000,b001,b010,b011,b100,b101,b110,b111;
    float awx, awy, awz, bwx, bwy, bwz;
    point_setup(axc, ayc, azc, a000,a001,a010,a011,a100,a101,a110,a111, awx, awy, awz);
    point_setup(bxc, byc, bzc, b000,b001,b010,b011,b100,b101,b110,b111, bwx, bwy, bwz);

    const uint2* __restrict__ wb0 = bricks;
    const uint2* __restrict__ wb1 = bricks + (size_t)BRICKS_PER_BATCH * 8;

    // issue all 16 gathers before any use (16 outstanding misses/thread)
    uint2 uA000 = wb0[a000], uA001 = wb0[a001], uA010 = wb0[a010], uA011 = wb0[a011];
    uint2 uA100 = wb0[a100], uA101 = wb0[a101], uA110 = wb0[a110], uA111 = wb0[a111];
    uint2 uB000 = wb1[b000], uB001 = wb1[b001], uB010 = wb1[b010], uB011 = wb1[b011];
    uint2 uB100 = wb1[b100], uB101 = wb1[b101], uB110 = wb1[b110], uB111 = wb1[b111];

    float4 cA00 = f4_lerp(vox_to_f4(uA000), vox_to_f4(uA001), awz);
    float4 cA01 = f4_lerp(vox_to_f4(uA010), vox_to_f4(uA011), awz);
    float4 cA10 = f4_lerp(vox_to_f4(uA100), vox_to_f4(uA101), awz);
    float4 cA11 = f4_lerp(vox_to_f4(uA110), vox_to_f4(uA111), awz);
    float4 cA0  = f4_lerp(cA00, cA01, awy);
    float4 cA1  = f4_lerp(cA10, cA11, awy);
    nt_store4(f4_lerp(cA0, cA1, awx), &out[idx]);

    float4 cB00 = f4_lerp(vox_to_f4(uB000), vox_to_f4(uB001), bwz);
    float4 cB01 = f4_lerp(vox_to_f4(uB010), vox_to_f4(uB011), bwz);
    float4 cB10 = f4_lerp(vox_to_f4(uB100), vox_to_f4(uB101), bwz);
    float4 cB11 = f4_lerp(vox_to_f4(uB110), vox_to_f4(uB111), bwz);
    float4 cB0  = f4_lerp(cB00, cB01, bwy);
    float4 cB1  = f4_lerp(cB10, cB11, bwy);
    nt_store4(f4_lerp(cB0, cB1, bwx), &out[idxB]);
}

// ---------------- Fallback: direct fp32 gather (if ws too small) -----------
__global__ __launch_bounds__(256) void resample_direct(
    const float4* __restrict__ in,
    const float*  __restrict__ coords,
    float4*       __restrict__ out)
{
    int idx = blockIdx.x * blockDim.x + threadIdx.x;
    if (idx >= TOTAL) return;

    const float cx = coords[3 * idx + 0];
    const float cy = coords[3 * idx + 1];
    const float cz = coords[3 * idx + 2];
    const float fx = floorf(cx), fy = floorf(cy), fz = floorf(cz);
    const float wx = cx - fx, wy = cy - fy, wz = cz - fz;

    int x0 = max(0, min((int)fx,     NS - 1));
    int x1 = max(0, min((int)fx + 1, NS - 1));
    int y0 = max(0, min((int)fy,     NS - 1));
    int y1 = max(0, min((int)fy + 1, NS - 1));
    int z0 = max(0, min((int)fz,     NS - 1));
    int z1 = max(0, min((int)fz + 1, NS - 1));

    const int b = idx / PPB;
    const float4* __restrict__ inb = in + (size_t)b * (NS * NS * NS);
    const float4* r00 = inb + ((size_t)x0 * NS + y0) * NS;
    const float4* r01 = inb + ((size_t)x0 * NS + y1) * NS;
    const float4* r10 = inb + ((size_t)x1 * NS + y0) * NS;
    const float4* r11 = inb + ((size_t)x1 * NS + y1) * NS;

    float4 c00 = f4_lerp(r00[z0], r00[z1], wz);
    float4 c01 = f4_lerp(r01[z0], r01[z1], wz);
    float4 c10 = f4_lerp(r10[z0], r10[z1], wz);
    float4 c11 = f4_lerp(r11[z0], r11[z1], wz);
    float4 c0 = f4_lerp(c00, c01, wy);
    float4 c1 = f4_lerp(c10, c11, wy);
    out[idx] = f4_lerp(c0, c1, wx);
}

extern "C" void kernel_launch(void* const* d_in, const int* in_sizes, int n_in,
                              void* d_out, int out_size, void* d_ws, size_t ws_size,
                              hipStream_t stream) {
    const float*  coords = (const float*)d_in[1];

    if (ws_size >= WS_NEEDED) {
        uint2* bricks = (uint2*)d_ws;
        int rp_threads = TOTAL_BRICKS * 8;                 // 4194304
        repack_fp16_bricks<<<rp_threads / 256, 256, 0, stream>>>((const fx4*)d_in[0], bricks);
        // one thread per (batch0, batch1) point pair; PPB = 3456 * 256 exactly
        resample_bricks2<<<PPB / 256, 256, 0, stream>>>(bricks, coords, (fx4*)d_out);
    } else {
        resample_direct<<<(TOTAL + 255) / 256, 256, 0, stream>>>(
            (const float4*)d_in[0], coords, (float4*)d_out);
    }
}